// Round 1
// baseline (123.513 us; speedup 1.0000x reference)
//
#include <hip/hip_runtime.h>
#include <math.h>

// LaplacianBuilder: N=2048 nodes, DEG=16, D=4, E=32768 edges (2E=65536 directed)
// out = dense (8192 x 8192) fp32 Laplacian, 256 MB, ~1.6% nonzero blocks.

// ---------------------------------------------------------------------------
// Kernel 1: accumulate per-node Gram matrices  diag[node] += M_e^T M_e
// ---------------------------------------------------------------------------
__global__ void accum_diag_kernel(const float* __restrict__ maps,
                                  const int* __restrict__ row_all,
                                  float* __restrict__ diag,
                                  int twoE) {
    int e = blockIdx.x * blockDim.x + threadIdx.x;
    if (e >= twoE) return;
    const float4* mp = reinterpret_cast<const float4*>(maps + (size_t)e * 16);
    float4 q0 = mp[0], q1 = mp[1], q2 = mp[2], q3 = mp[3];
    float m[4][4] = {
        {q0.x, q0.y, q0.z, q0.w},
        {q1.x, q1.y, q1.z, q1.w},
        {q2.x, q2.y, q2.z, q2.w},
        {q3.x, q3.y, q3.z, q3.w},
    };
    int node = row_all[e];
    float* dst = diag + (size_t)node * 16;
    #pragma unroll
    for (int i = 0; i < 4; ++i) {
        #pragma unroll
        for (int j = i; j < 4; ++j) {
            float cc = m[0][i] * m[0][j] + m[1][i] * m[1][j] +
                       m[2][i] * m[2][j] + m[3][i] * m[3][j];
            atomicAdd(dst + i * 4 + j, cc);
            if (i != j) atomicAdd(dst + j * 4 + i, cc);
        }
    }
}

// ---------------------------------------------------------------------------
// Jacobi rotation on (P,Q), all indices compile-time constant -> registers
// ---------------------------------------------------------------------------
template <int P, int Q>
__device__ __forceinline__ void jrot(float a[4][4], float v[4][4]) {
    float apq = a[P][Q];
    if (fabsf(apq) < 1e-12f) return;
    float theta = (a[Q][Q] - a[P][P]) / (2.0f * apq);
    float t = 1.0f / (fabsf(theta) + sqrtf(theta * theta + 1.0f));
    t = (theta < 0.0f) ? -t : t;
    float c = 1.0f / sqrtf(t * t + 1.0f);
    float s = t * c;
    #pragma unroll
    for (int k = 0; k < 4; ++k) {   // A <- A J
        float akp = a[k][P], akq = a[k][Q];
        a[k][P] = c * akp - s * akq;
        a[k][Q] = s * akp + c * akq;
    }
    #pragma unroll
    for (int k = 0; k < 4; ++k) {   // A <- J^T A
        float apk = a[P][k], aqk = a[Q][k];
        a[P][k] = c * apk - s * aqk;
        a[Q][k] = s * apk + c * aqk;
    }
    #pragma unroll
    for (int k = 0; k < 4; ++k) {   // V <- V J
        float vkp = v[k][P], vkq = v[k][Q];
        v[k][P] = c * vkp - s * vkq;
        v[k][Q] = s * vkp + c * vkq;
    }
}

// ---------------------------------------------------------------------------
// Kernel 2: per node, eigh(D + I) -> S = (D+I)^(-1/2); store S; write diag
// block  clip(S D S, -1, 1)  into out.
// ---------------------------------------------------------------------------
__global__ void node_kernel(const float* __restrict__ diag,
                            float* __restrict__ Smat,
                            float* __restrict__ out,
                            int n, int ld) {
    int node = blockIdx.x * blockDim.x + threadIdx.x;
    if (node >= n) return;
    const float4* dp = reinterpret_cast<const float4*>(diag + (size_t)node * 16);
    float4 q0 = dp[0], q1 = dp[1], q2 = dp[2], q3 = dp[3];
    float dmat[4][4] = {
        {q0.x, q0.y, q0.z, q0.w},
        {q1.x, q1.y, q1.z, q1.w},
        {q2.x, q2.y, q2.z, q2.w},
        {q3.x, q3.y, q3.z, q3.w},
    };
    float a[4][4], v[4][4];
    #pragma unroll
    for (int i = 0; i < 4; ++i) {
        #pragma unroll
        for (int j = 0; j < 4; ++j) {
            a[i][j] = dmat[i][j] + (i == j ? 1.0f : 0.0f);
            v[i][j] = (i == j) ? 1.0f : 0.0f;
        }
    }
    #pragma unroll
    for (int sweep = 0; sweep < 6; ++sweep) {
        jrot<0, 1>(a, v); jrot<0, 2>(a, v); jrot<0, 3>(a, v);
        jrot<1, 2>(a, v); jrot<1, 3>(a, v); jrot<2, 3>(a, v);
    }
    float ir[4];
    #pragma unroll
    for (int m = 0; m < 4; ++m)
        ir[m] = 1.0f / sqrtf(fmaxf(a[m][m], 1e-8f));
    float s[4][4];
    #pragma unroll
    for (int i = 0; i < 4; ++i) {
        #pragma unroll
        for (int j = 0; j < 4; ++j) {
            s[i][j] = v[i][0] * v[j][0] * ir[0] + v[i][1] * v[j][1] * ir[1] +
                      v[i][2] * v[j][2] * ir[2] + v[i][3] * v[j][3] * ir[3];
        }
    }
    float4* sp = reinterpret_cast<float4*>(Smat + (size_t)node * 16);
    sp[0] = make_float4(s[0][0], s[0][1], s[0][2], s[0][3]);
    sp[1] = make_float4(s[1][0], s[1][1], s[1][2], s[1][3]);
    sp[2] = make_float4(s[2][0], s[2][1], s[2][2], s[2][3]);
    sp[3] = make_float4(s[3][0], s[3][1], s[3][2], s[3][3]);
    // dd = clip(S * D * S, -1, 1)
    float t1[4][4];
    #pragma unroll
    for (int i = 0; i < 4; ++i)
        #pragma unroll
        for (int j = 0; j < 4; ++j)
            t1[i][j] = s[i][0] * dmat[0][j] + s[i][1] * dmat[1][j] +
                       s[i][2] * dmat[2][j] + s[i][3] * dmat[3][j];
    float dd[4][4];
    #pragma unroll
    for (int i = 0; i < 4; ++i)
        #pragma unroll
        for (int j = 0; j < 4; ++j) {
            float x = t1[i][0] * s[0][j] + t1[i][1] * s[1][j] +
                      t1[i][2] * s[2][j] + t1[i][3] * s[3][j];
            dd[i][j] = fminf(fmaxf(x, -1.0f), 1.0f);
        }
    size_t base = ((size_t)node * 4) * (size_t)ld + (size_t)node * 4;
    #pragma unroll
    for (int i = 0; i < 4; ++i)
        *reinterpret_cast<float4*>(out + base + (size_t)i * ld) =
            make_float4(dd[i][0], dd[i][1], dd[i][2], dd[i][3]);
}

// ---------------------------------------------------------------------------
// Kernel 3/4: per edge, T = clip(S_r (A^T B) S_c, -1, 1)
//   PASS 0: out[r,c] block = -T        (reference scatter #1)
//   PASS 1: out[c,r] block = -T^T      (reference scatter #2 — wins conflicts,
//                                       hence launched strictly after PASS 0)
// ---------------------------------------------------------------------------
template <int PASS>
__global__ void scatter_kernel(const float* __restrict__ maps,
                               const int* __restrict__ ei,
                               const float* __restrict__ Smat,
                               float* __restrict__ out,
                               int E, int twoE, int ld) {
    int e = blockIdx.x * blockDim.x + threadIdx.x;
    if (e >= E) return;
    int r = ei[e];
    int c = ei[twoE + e];
    const float4* ap = reinterpret_cast<const float4*>(maps + (size_t)e * 16);
    const float4* bp = reinterpret_cast<const float4*>(maps + (size_t)(E + e) * 16);
    float4 a0 = ap[0], a1 = ap[1], a2 = ap[2], a3 = ap[3];
    float4 b0 = bp[0], b1 = bp[1], b2 = bp[2], b3 = bp[3];
    float A[4][4] = {{a0.x, a0.y, a0.z, a0.w}, {a1.x, a1.y, a1.z, a1.w},
                     {a2.x, a2.y, a2.z, a2.w}, {a3.x, a3.y, a3.z, a3.w}};
    float B[4][4] = {{b0.x, b0.y, b0.z, b0.w}, {b1.x, b1.y, b1.z, b1.w},
                     {b2.x, b2.y, b2.z, b2.w}, {b3.x, b3.y, b3.z, b3.w}};
    // C = A^T B
    float C[4][4];
    #pragma unroll
    for (int i = 0; i < 4; ++i)
        #pragma unroll
        for (int j = 0; j < 4; ++j)
            C[i][j] = A[0][i] * B[0][j] + A[1][i] * B[1][j] +
                      A[2][i] * B[2][j] + A[3][i] * B[3][j];
    const float4* srp = reinterpret_cast<const float4*>(Smat + (size_t)r * 16);
    const float4* scp = reinterpret_cast<const float4*>(Smat + (size_t)c * 16);
    float4 s0 = srp[0], s1 = srp[1], s2 = srp[2], s3 = srp[3];
    float Sr[4][4] = {{s0.x, s0.y, s0.z, s0.w}, {s1.x, s1.y, s1.z, s1.w},
                      {s2.x, s2.y, s2.z, s2.w}, {s3.x, s3.y, s3.z, s3.w}};
    float4 c0 = scp[0], c1 = scp[1], c2 = scp[2], c3 = scp[3];
    float Sc[4][4] = {{c0.x, c0.y, c0.z, c0.w}, {c1.x, c1.y, c1.z, c1.w},
                      {c2.x, c2.y, c2.z, c2.w}, {c3.x, c3.y, c3.z, c3.w}};
    float t1[4][4];
    #pragma unroll
    for (int i = 0; i < 4; ++i)
        #pragma unroll
        for (int j = 0; j < 4; ++j)
            t1[i][j] = Sr[i][0] * C[0][j] + Sr[i][1] * C[1][j] +
                       Sr[i][2] * C[2][j] + Sr[i][3] * C[3][j];
    float W[4][4];  // W = -clip(T)
    #pragma unroll
    for (int i = 0; i < 4; ++i)
        #pragma unroll
        for (int j = 0; j < 4; ++j) {
            float x = t1[i][0] * Sc[0][j] + t1[i][1] * Sc[1][j] +
                      t1[i][2] * Sc[2][j] + t1[i][3] * Sc[3][j];
            W[i][j] = -fminf(fmaxf(x, -1.0f), 1.0f);
        }
    if (PASS == 0) {
        size_t base = ((size_t)r * 4) * (size_t)ld + (size_t)c * 4;
        #pragma unroll
        for (int i = 0; i < 4; ++i)
            *reinterpret_cast<float4*>(out + base + (size_t)i * ld) =
                make_float4(W[i][0], W[i][1], W[i][2], W[i][3]);
    } else {
        size_t base = ((size_t)c * 4) * (size_t)ld + (size_t)r * 4;
        #pragma unroll
        for (int i = 0; i < 4; ++i)   // row i of -T^T is column i of W
            *reinterpret_cast<float4*>(out + base + (size_t)i * ld) =
                make_float4(W[0][i], W[1][i], W[2][i], W[3][i]);
    }
}

extern "C" void kernel_launch(void* const* d_in, const int* in_sizes, int n_in,
                              void* d_out, int out_size, void* d_ws, size_t ws_size,
                              hipStream_t stream) {
    const float* maps = (const float*)d_in[0];
    const int* ei = (const int*)d_in[1];  // (2, 2E) int32
    int twoE = in_sizes[0] / 16;          // 65536
    int E = twoE / 2;                     // 32768
    const int n = 2048;                   // reference module constant N_NODES
    const int ld = n * 4;                 // 8192

    float* out = (float*)d_out;
    float* ws_diag = (float*)d_ws;                    // n*16 floats
    float* ws_S = ws_diag + (size_t)n * 16;           // n*16 floats

    // zero the Gram accumulator and the dense output
    hipMemsetAsync(ws_diag, 0, (size_t)n * 16 * sizeof(float), stream);
    hipMemsetAsync(d_out, 0, (size_t)out_size * sizeof(float), stream);

    accum_diag_kernel<<<(twoE + 255) / 256, 256, 0, stream>>>(maps, ei, ws_diag, twoE);
    node_kernel<<<(n + 255) / 256, 256, 0, stream>>>(ws_diag, ws_S, out, n, ld);
    scatter_kernel<0><<<(E + 255) / 256, 256, 0, stream>>>(maps, ei, ws_S, out, E, twoE, ld);
    scatter_kernel<1><<<(E + 255) / 256, 256, 0, stream>>>(maps, ei, ws_S, out, E, twoE, ld);
}